// Round 2
// 125.565 us; speedup vs baseline: 1.0307x; 1.0307x over previous
//
#include <hip/hip_runtime.h>

// MaskToken: B=4, L=4096, D=1024, NUM_KEEP=1024 (sorted idx_keep), NUM_DROP=3072.
// Outputs (concat, float32 view):
//   out0 = outputs_dropped  [B, NUM_KEEP, D]   = gather of kept rows
//   out1 = outputs_masked   [B, L, D]          = kept rows passthrough, dropped rows = mask_embedding
//   out2 = mask_drop        [L]                = 1.0 where dropped else 0.0
//   out3 = idx_keep         [NUM_KEEP]         = written as float values
//
// One block per (b,l) row; 256 threads x float4 = 1024 floats.
// Rank/keep lookup: instead of a 10-step DEPENDENT binary search (10 serial
// wave-uniform loads ~0.4-1us of chain latency per block), all 256 threads
// probe the entire 1024-entry sorted idx_keep in ONE int4 L1-resident load;
// the unique matching thread broadcasts its rank via a 4B LDS slot.
// Traffic is already minimal (dropped rows never read `in`), so this targets
// per-block startup latency, the gap between ~25-30us observed and the
// ~15.5us memory floor (100.7 MB @ 6.6 TB/s).

#define B_ 4
#define L_ 4096
#define D_ 1024
#define NKEEP_ 1024

__global__ __launch_bounds__(256) void masktoken_kernel(
    const float4* __restrict__ in,        // [B*L*D/4]
    const float4* __restrict__ me,        // [D/4] mask embedding
    const int4*   __restrict__ idx_keep4, // [NKEEP_/4] sorted
    float4* __restrict__ out0,            // [B*NKEEP_*D/4]
    float4* __restrict__ out1,            // [B*L*D/4]
    float*  __restrict__ out2,            // [L]
    float*  __restrict__ out3)            // [NKEEP_]
{
    const int row = blockIdx.x;           // 0 .. B*L-1
    const int b   = row >> 12;            // row / L
    const int l   = row & (L_ - 1);       // row % L
    const int t   = threadIdx.x;          // 0..255 -> float4 slot in row

    __shared__ int sr;

    // Issue both independent L1-resident loads immediately so their latency
    // overlaps the barrier/compare sequence below.
    const int4   kv = idx_keep4[t];       // ranks 4t..4t+3 of the keep table
    const float4 mv = me[t];              // mask-embedding quad for this slot

    if (t == 0) sr = -1;
    __syncthreads();

    int m = -1;
    if (kv.x == l) m = 4 * t + 0;
    if (kv.y == l) m = 4 * t + 1;
    if (kv.z == l) m = 4 * t + 2;
    if (kv.w == l) m = 4 * t + 3;
    if (m >= 0) sr = m;                   // at most one thread matches
    __syncthreads();

    const int r = sr;                     // rank in idx_keep, or -1 if dropped

    const size_t rowOff = (size_t)row * (D_ / 4);
    if (r >= 0) {
        float4 v = in[rowOff + t];
        out1[rowOff + t] = v;                                      // passthrough
        out0[((size_t)b * NKEEP_ + (size_t)r) * (D_ / 4) + t] = v; // gather
    } else {
        out1[rowOff + t] = mv;                                     // mask embedding
    }

    if (b == 0 && t == 0) {
        out2[l] = (r < 0) ? 1.0f : 0.0f;
        if (r >= 0) out3[r] = (float)l;   // idx_keep[r] == l by construction
    }
}

extern "C" void kernel_launch(void* const* d_in, const int* in_sizes, int n_in,
                              void* d_out, int out_size, void* d_ws, size_t ws_size,
                              hipStream_t stream) {
    const float4* in  = (const float4*)d_in[0];       // inputs [B,L,D]
    const float4* me  = (const float4*)d_in[1];       // mask_embedding [D]
    const int4*   idx = (const int4*)d_in[2];         // idx_keep [NKEEP_]

    float* out = (float*)d_out;
    float4* out0 = (float4*)out;                                  // B*NKEEP_*D
    float4* out1 = (float4*)(out + (size_t)B_ * NKEEP_ * D_);     // B*L*D
    float*  out2 = out + (size_t)B_ * NKEEP_ * D_ + (size_t)B_ * L_ * D_;  // L
    float*  out3 = out2 + L_;                                     // NKEEP_

    dim3 grid(B_ * L_);
    dim3 block(256);
    masktoken_kernel<<<grid, block, 0, stream>>>(in, me, idx, out0, out1, out2, out3);
}